// Round 10
// baseline (334.240 us; speedup 1.0000x reference)
//
#include <hip/hip_runtime.h>
#include <stdint.h>

#define NN 100000
#define NE 1600000
#define DIN 500
#define DH 64
#define DOUT 8
#define KP 512          // K padded to 16 mfma steps of 32
#define MAXDEG 64       // P(in-deg+self >= 64) ~ 1e-19 for Poisson(17)
#define XBYTES ((size_t)NN * DIN * 4)   // 200 MB

#define FILL_EPT 4
#define FILL_PASSES 16
#define FILL_RS ((NN + FILL_PASSES - 1) / FILL_PASSES)   // 6250 nodes per pass
#define GEMMB ((NN + 63) / 64)

typedef __attribute__((ext_vector_type(8))) short short8;
typedef __attribute__((ext_vector_type(4))) float f32x4;
typedef unsigned short ushort_t;

static __device__ __forceinline__ ushort_t f2bf(float f) {
  union { float f; uint32_t u; } v; v.f = f;
  uint32_t u = v.u;
  return (ushort_t)((u + 0x7FFFu + ((u >> 16) & 1u)) >> 16);  // RTN-even
}
static __device__ __forceinline__ float bf2f(ushort_t h) {
  union { uint32_t u; float f; } v; v.u = ((uint32_t)h) << 16;
  return v.f;
}

static __device__ __forceinline__ void gload16(const void* g, void* l) {
  __builtin_amdgcn_global_load_lds((const __attribute__((address_space(1))) uint32_t*)g,
                                   (__attribute__((address_space(3))) uint32_t*)l, 16, 0, 0);
}

// Standalone fill (reverted from fusion): 4-VGPR, no-LDS kernel -> ~all 1661 blocks
// co-resident, so the 16 dst-range passes align chip-wide and colsrc stores merge in L2.
__global__ __launch_bounds__(256) void k_fill(const int* __restrict__ ei,
                                              int* __restrict__ cursor,
                                              int* __restrict__ colsrc) {
  int t = blockIdx.x * 256 + threadIdx.x;
  const int T = gridDim.x * 256;
  int s[FILL_EPT], d[FILL_EPT];
#pragma unroll
  for (int k = 0; k < FILL_EPT; ++k) {
    int id = t + k * T;
    s[k] = 0; d[k] = -1;
    if (id < NE) { s[k] = ei[id]; d[k] = ei[NE + id]; }
    else if (id < NE + NN) { s[k] = id - NE; d[k] = s[k]; }   // self-loops
  }
#pragma unroll 1
  for (int p = 0; p < FILL_PASSES; ++p) {
    int lo = p * FILL_RS;
    int hi = lo + FILL_RS;
#pragma unroll
    for (int k = 0; k < FILL_EPT; ++k) {
      bool act = (d[k] >= lo) && (d[k] < hi);
      if (__any(act)) {
        if (act) {
          int pos = atomicAdd(&cursor[d[k]], 1);
          if (pos < MAXDEG) colsrc[d[k] * MAXDEG + pos] = s[k];
        }
      }
    }
  }
}

__global__ __launch_bounds__(256) void k_dinv(const int* __restrict__ cursor,
                                              float* __restrict__ dinv) {
  int v = blockIdx.x * 256 + threadIdx.x;
  if (v >= NN) return;
  dinv[v] = 1.0f / sqrtf((float)cursor[v]);    // deg >= 1 always (self-loop)
}

// W1 -> bf16 hi/lo fragment table bt:
// id = (((kkg*4+off)*2 + h)*64 + lane)*8 + i ; col = off*16+(lane&15); k = kkg*32+(lane>>4)*8+i
__global__ __launch_bounds__(256) void k_w1cvt(const float* __restrict__ W1,
                                               ushort_t* __restrict__ bt) {
  int id = blockIdx.x * 256 + threadIdx.x;
  if (id >= DH * KP * 2) return;
  int i = id & 7, lane = (id >> 3) & 63, h = (id >> 9) & 1;
  int off = (id >> 10) & 3, kkg = id >> 12;
  int r = lane & 15, g = lane >> 4;
  int col = off * 16 + r;
  int k = kkg * 32 + g * 8 + i;
  float v = (k < DIN) ? W1[k * DH + col] : 0.0f;
  ushort_t hi = f2bf(v);
  bt[id] = h ? f2bf(v - bf2f(hi)) : hi;
}

// hw = xs @ W1: gload_lds A-staging (dbuf) + B ping-pong. xs may be the fresh copy
// in workspace; REVERSED block order reads the most-recently-copied (L3-hot) rows first.
__global__ __launch_bounds__(256) void k_gemm1(const float* __restrict__ xs,
                                               const ushort_t* __restrict__ bt,
                                               ushort_t* __restrict__ hwb) {
  __shared__ float lds[2][64 * 128];
  int tid = threadIdx.x;
  int lane = tid & 63, w = tid >> 6;
  int r = lane & 15, g = lane >> 4;
  int gid = (GEMMB - 1) - blockIdx.x;          // tail-first: copy tail is L3-resident
  int row0 = gid * 64;
  int rowl = w * 16 + r;

  auto stage = [&](int ch, int b) {
    float* base = &lds[b][0];
#pragma unroll
    for (int j = 0; j < 8; ++j) {
      int idx = j * 256 + tid;
      int row = idx >> 5, q = idx & 31;
      int kq = ch * 32 + q; if (kq > 124) kq = 124;     // dup region hits zero B cols
      int grow = row0 + row; if (grow >= NN) grow = NN - 1;
      gload16(xs + (size_t)grow * DIN + kq * 4, base + idx * 4);
    }
  };

  short8 Bc[8], Bn[8];
  auto loadB = [&](short8* B, int kkg) {
    const ushort_t* bp = bt + (size_t)kkg * 8 * 512 + lane * 8;
#pragma unroll
    for (int u = 0; u < 8; ++u) B[u] = *(const short8*)(bp + u * 512);
  };

  f32x4 acc0 = {0,0,0,0}, acc1 = {0,0,0,0}, acc2 = {0,0,0,0}, acc3 = {0,0,0,0};

  auto compute = [&](int ch, int kk, const short8* B) {
    const float* lp = &lds[ch & 1][rowl * 128 + (kk * 8 + g * 2) * 4];
    f32x4 v0 = *(const f32x4*)lp;
    f32x4 v1 = *(const f32x4*)(lp + 4);
    float a[8] = {v0.x, v0.y, v0.z, v0.w, v1.x, v1.y, v1.z, v1.w};
    short8 ah, al;
#pragma unroll
    for (int i = 0; i < 8; ++i) {
      ushort_t hi = f2bf(a[i]);
      ah[i] = (short)hi;
      al[i] = (short)f2bf(a[i] - bf2f(hi));
    }
#define TILE(T, OFF)                                                          \
    T = __builtin_amdgcn_mfma_f32_16x16x32_bf16(ah, B[(OFF)*2],   T, 0, 0, 0);\
    T = __builtin_amdgcn_mfma_f32_16x16x32_bf16(al, B[(OFF)*2],   T, 0, 0, 0);\
    T = __builtin_amdgcn_mfma_f32_16x16x32_bf16(ah, B[(OFF)*2+1], T, 0, 0, 0);
    TILE(acc0, 0) TILE(acc1, 1) TILE(acc2, 2) TILE(acc3, 3)
#undef TILE
  };

  loadB(Bc, 0);
  stage(0, 0);
  __syncthreads();
#pragma unroll 1
  for (int ch = 0; ch < 4; ++ch) {
    if (ch < 3) stage(ch + 1, (ch + 1) & 1);   // DMA next chunk, in flight across compute
    int k0 = ch * 4;
    loadB(Bn, k0 + 1);  compute(ch, 0, Bc);    // ping-pong: issue B[k+1], use B[k]
    loadB(Bc, k0 + 2);  compute(ch, 1, Bn);
    loadB(Bn, k0 + 3);  compute(ch, 2, Bc);
    if (ch < 3) loadB(Bc, k0 + 4);
    compute(ch, 3, Bn);
    __syncthreads();                           // drains stage DMA + buffer reuse
  }
  int wrow0 = row0 + w * 16;
#pragma unroll
  for (int i = 0; i < 4; ++i) {
    int orow = wrow0 + g * 4 + i;              // C/D: row=(lane>>4)*4+reg, col=lane&15
    if (orow < NN) {
      ushort_t* o = hwb + (size_t)orow * DH + r;
      o[0]  = f2bf(acc0[i]);
      o[16] = f2bf(acc1[i]);
      o[32] = f2bf(acc2[i]);
      o[48] = f2bf(acc3[i]);
    }
  }
}

// Layer-1 aggregate (gather, 16-deep MLP) + bias + ReLU + fused h@W2 -> hw2[v][0..7]
__global__ __launch_bounds__(256) void k_agg1(const ushort_t* __restrict__ hwb,
                                              const int* __restrict__ colsrc,
                                              const int* __restrict__ cnt,
                                              const float* __restrict__ dinv,
                                              const float* __restrict__ b1,
                                              const float* __restrict__ W2,
                                              float* __restrict__ hw2) {
  int lane = threadIdx.x & 63;
  int v = blockIdx.x * 4 + (threadIdx.x >> 6);
  if (v >= NN) return;
  int c = cnt[v]; if (c > MAXDEG) c = MAXDEG;
  float dv = dinv[v];
  const int* cl = colsrc + v * MAXDEG;
  int si = cl[lane];
  bool act = lane < c;
  if (!act) si = 0;
  float nrmv = act ? dinv[si] * dv : 0.0f;
  float acc = 0.0f;
  for (int i0 = 0; i0 < c; i0 += 16) {
    float val[16];
#pragma unroll
    for (int j = 0; j < 16; ++j) {
      int s = __builtin_amdgcn_readlane(si, i0 + j);
      val[j] = bf2f(hwb[(size_t)s * DH + lane]);
    }
#pragma unroll
    for (int j = 0; j < 16; ++j) {
      float nrm = __uint_as_float(__builtin_amdgcn_readlane(__float_as_uint(nrmv), i0 + j));
      acc = fmaf(val[j], nrm, acc);
    }
  }
  float h = acc + b1[lane];
  h = h > 0.0f ? h : 0.0f;
  const float* w2r = W2 + lane * DOUT;
  float p0 = h * w2r[0], p1 = h * w2r[1], p2 = h * w2r[2], p3 = h * w2r[3];
  float p4 = h * w2r[4], p5 = h * w2r[5], p6 = h * w2r[6], p7 = h * w2r[7];
#pragma unroll
  for (int off = 32; off > 0; off >>= 1) {
    p0 += __shfl_xor(p0, off); p1 += __shfl_xor(p1, off);
    p2 += __shfl_xor(p2, off); p3 += __shfl_xor(p3, off);
    p4 += __shfl_xor(p4, off); p5 += __shfl_xor(p5, off);
    p6 += __shfl_xor(p6, off); p7 += __shfl_xor(p7, off);
  }
  if (lane == 0) {
    float4 q0 = {p0, p1, p2, p3}, q1 = {p4, p5, p6, p7};
    *(float4*)(hw2 + (size_t)v * DOUT)     = q0;
    *(float4*)(hw2 + (size_t)v * DOUT + 4) = q1;
  }
}

// Layer-2 aggregate + bias + log_softmax. One WAVE per node: lanes = 8 edges x 8 features.
__global__ __launch_bounds__(256) void k_agg2(const float* __restrict__ hw2,
                                              const int* __restrict__ colsrc,
                                              const int* __restrict__ cnt,
                                              const float* __restrict__ dinv,
                                              const float* __restrict__ b2,
                                              float* __restrict__ out) {
  int lane = threadIdx.x & 63;
  int v = blockIdx.x * 4 + (threadIdx.x >> 6);
  if (v >= NN) return;
  int e = lane >> 3, f = lane & 7;
  int c = cnt[v]; if (c > MAXDEG) c = MAXDEG;
  float dv = dinv[v];
  const int* cl = colsrc + v * MAXDEG;
  float acc = 0.0f;
  for (int i0 = 0; i0 < c; i0 += 8) {
    int i = i0 + e;
    bool a2 = i < c;
    int s = a2 ? cl[i] : 0;
    float nrm = a2 ? dinv[s] * dv : 0.0f;
    float val = hw2[(size_t)s * DOUT + f] * nrm;
    val += __shfl_xor(val, 8);
    val += __shfl_xor(val, 16);
    val += __shfl_xor(val, 32);
    acc += val;
  }
  acc += b2[f];
  float m = acc;
  m = fmaxf(m, __shfl_xor(m, 1));
  m = fmaxf(m, __shfl_xor(m, 2));
  m = fmaxf(m, __shfl_xor(m, 4));
  float ex = expf(acc - m);
  float sum = ex;
  sum += __shfl_xor(sum, 1);
  sum += __shfl_xor(sum, 2);
  sum += __shfl_xor(sum, 4);
  float ls = m + logf(sum);
  if (e == 0) out[(size_t)v * DOUT + f] = acc - ls;
}

extern "C" void kernel_launch(void* const* d_in, const int* in_sizes, int n_in,
                              void* d_out, int out_size, void* d_ws, size_t ws_size,
                              hipStream_t stream) {
  const float* x  = (const float*)d_in[0];
  const int*   ei = (const int*)d_in[1];
  const float* W1 = (const float*)d_in[2];
  const float* b1 = (const float*)d_in[3];
  const float* W2 = (const float*)d_in[4];
  const float* b2 = (const float*)d_in[5];
  float* out = (float*)d_out;

  char* w = (char*)d_ws;
  size_t off = 0;
  auto alloc = [&](size_t bytes) {
    char* p = w + off;
    off += (bytes + 255) & ~(size_t)255;
    return (void*)p;
  };
  int*      cursor = (int*)alloc((size_t)NN * 4);
  float*    dinv   = (float*)alloc((size_t)NN * 4);
  ushort_t* bt     = (ushort_t*)alloc((size_t)DH * KP * 2 * 2);
  int*      colsrc = (int*)alloc((size_t)NN * MAXDEG * 4);
  ushort_t* hwb    = (ushort_t*)alloc((size_t)NN * DH * 2);
  float*    hw2    = (float*)alloc((size_t)NN * DOUT * 4);

  // Instrument + potential win: copy x into local workspace with the runtime's
  // tuned copy kernel; gemm then reads the (tail-L3-hot) copy. Guarded by ws_size.
  const float* xsrc = x;
  if (ws_size >= off + XBYTES + 256) {
    float* xcopy = (float*)alloc(XBYTES);
    hipMemcpyAsync(xcopy, x, XBYTES, hipMemcpyDeviceToDevice, stream);
    xsrc = xcopy;
  }

  hipMemsetAsync(cursor, 0, (size_t)NN * 4, stream);
  int fill_blocks = (NE + NN + 256 * FILL_EPT - 1) / (256 * FILL_EPT);
  k_fill<<<fill_blocks, 256, 0, stream>>>(ei, cursor, colsrc);
  k_dinv<<<(NN + 255) / 256, 256, 0, stream>>>(cursor, dinv);
  k_w1cvt<<<(DH * KP * 2 + 255) / 256, 256, 0, stream>>>(W1, bt);
  k_gemm1<<<GEMMB, 256, 0, stream>>>(xsrc, bt, hwb);
  k_agg1<<<(NN + 3) / 4, 256, 0, stream>>>(hwb, colsrc, cursor, dinv, b1, W2, hw2);
  k_agg2<<<(NN + 3) / 4, 256, 0, stream>>>(hw2, colsrc, cursor, dinv, b2, out);
}

// Round 11
// 264.966 us; speedup vs baseline: 1.2614x; 1.2614x over previous
//
#include <hip/hip_runtime.h>
#include <stdint.h>

#define NN 100000
#define NE 1600000
#define DIN 500
#define DH 64
#define DOUT 8
#define KP 512          // K padded to 16 mfma steps of 32
#define MAXDEG 64       // P(in-deg+self >= 64) ~ 1e-19 for Poisson(17)
#define MAXQ (NN * 125) // total 16B-quads in x

#define FILL_EPT 4
#define FILL_PASSES 16
#define FILL_RS ((NN + FILL_PASSES - 1) / FILL_PASSES)   // 6250 nodes per pass
#define GEMMB ((NN + 63) / 64)

typedef __attribute__((ext_vector_type(8))) short short8;
typedef __attribute__((ext_vector_type(4))) float f32x4;
typedef unsigned short ushort_t;

static __device__ __forceinline__ ushort_t f2bf(float f) {
  union { float f; uint32_t u; } v; v.f = f;
  uint32_t u = v.u;
  return (ushort_t)((u + 0x7FFFu + ((u >> 16) & 1u)) >> 16);  // RTN-even
}
static __device__ __forceinline__ float bf2f(ushort_t h) {
  union { uint32_t u; float f; } v; v.u = ((uint32_t)h) << 16;
  return v.f;
}

static __device__ __forceinline__ void gload16(const void* g, void* l) {
  __builtin_amdgcn_global_load_lds((const __attribute__((address_space(1))) uint32_t*)g,
                                   (__attribute__((address_space(3))) uint32_t*)l, 16, 0, 0);
}

// Standalone fill: 4-VGPR no-LDS kernel, all blocks co-resident -> dst-range passes
// align chip-wide and colsrc stores merge in L2 before writeback.
__global__ __launch_bounds__(256) void k_fill(const int* __restrict__ ei,
                                              int* __restrict__ cursor,
                                              int* __restrict__ colsrc) {
  int t = blockIdx.x * 256 + threadIdx.x;
  const int T = gridDim.x * 256;
  int s[FILL_EPT], d[FILL_EPT];
#pragma unroll
  for (int k = 0; k < FILL_EPT; ++k) {
    int id = t + k * T;
    s[k] = 0; d[k] = -1;
    if (id < NE) { s[k] = ei[id]; d[k] = ei[NE + id]; }
    else if (id < NE + NN) { s[k] = id - NE; d[k] = s[k]; }   // self-loops
  }
#pragma unroll 1
  for (int p = 0; p < FILL_PASSES; ++p) {
    int lo = p * FILL_RS;
    int hi = lo + FILL_RS;
#pragma unroll
    for (int k = 0; k < FILL_EPT; ++k) {
      bool act = (d[k] >= lo) && (d[k] < hi);
      if (__any(act)) {
        if (act) {
          int pos = atomicAdd(&cursor[d[k]], 1);
          if (pos < MAXDEG) colsrc[d[k] * MAXDEG + pos] = s[k];
        }
      }
    }
  }
}

__global__ __launch_bounds__(256) void k_dinv(const int* __restrict__ cursor,
                                              float* __restrict__ dinv) {
  int v = blockIdx.x * 256 + threadIdx.x;
  if (v >= NN) return;
  dinv[v] = 1.0f / sqrtf((float)cursor[v]);    // deg >= 1 always (self-loop)
}

// W1 -> bf16 hi/lo fragment table bt:
// id = (((kkg*4+off)*2 + h)*64 + lane)*8 + i ; col = off*16+(lane&15); k = kkg*32+(lane>>4)*8+i
__global__ __launch_bounds__(256) void k_w1cvt(const float* __restrict__ W1,
                                               ushort_t* __restrict__ bt) {
  int id = blockIdx.x * 256 + threadIdx.x;
  if (id >= DH * KP * 2) return;
  int i = id & 7, lane = (id >> 3) & 63, h = (id >> 9) & 1;
  int off = (id >> 10) & 3, kkg = id >> 12;
  int r = lane & 15, g = lane >> 4;
  int col = off * 16 + r;
  int k = kkg * 32 + g * 8 + i;
  float v = (k < DIN) ? W1[k * DH + col] : 0.0f;
  ushort_t hi = f2bf(v);
  bt[id] = h ? f2bf(v - bf2f(hi)) : hi;
}

// hw = x @ W1, v6: DRAM-contiguous row-chunk staging + all-B-in-VGPR preload.
// Block = 64-row tile, 4 chunks of 16 FULL rows (32KB contiguous HBM stream each).
// Waves col-split the output (wave w = cols 16w..16w+15), so every wave computes on
// every chunk. B (wave's col-quadrant, all 16 kkg, hi+lo = 128 VGPRs) is preloaded
// ONCE before the loop: zero VMEM ops in the compute path -> the in-order vmcnt
// queue holds only staging DMA, never drained early (m135: vmcnt retires in order).
__global__ __launch_bounds__(256, 2) void k_gemm1(const float* __restrict__ x,
                                                  const ushort_t* __restrict__ bt,
                                                  ushort_t* __restrict__ hwb) {
  __shared__ float lds[2][8016];   // 16 rows x 500 floats + 16-float pad (kkg=15 overread)
  int tid = threadIdx.x;
  int lane = tid & 63, w = tid >> 6;
  int r = lane & 15, g = lane >> 4;
  int row0 = blockIdx.x * 64;

  // ---- B preload: this wave's col-quadrant, all K. 32 x short8 = 128 VGPRs.
  short8 Ball[32];
#pragma unroll
  for (int kkg = 0; kkg < 16; ++kkg) {
    const ushort_t* bp = bt + (size_t)((kkg * 4 + w) * 2) * 512 + lane * 8;
    Ball[kkg * 2]     = *(const short8*)bp;          // hi
    Ball[kkg * 2 + 1] = *(const short8*)(bp + 512);  // lo
  }

  auto stage = [&](int c, int b) {
    float* base = &lds[b][0];
    int q0 = (row0 + c * 16) * 125;          // first 16B-quad of this 16-row chunk
#pragma unroll
    for (int j = 0; j < 8; ++j) {
      int idx = j * 256 + tid;               // 0..2047; 2000 valid quads per chunk
      if (idx < 2000) {
        int q = q0 + idx;
        if (q >= MAXQ) q = MAXQ - 1;         // last-block clamp; results discarded
        gload16(x + (size_t)q * 4, base + idx * 4);
      }
    }
  };

  stage(0, 0);
  __syncthreads();                           // drains Ball + chunk0 DMA
#pragma unroll 1
  for (int c = 0; c < 4; ++c) {
    if (c < 3) stage(c + 1, (c + 1) & 1);    // contiguous 32KB DMA, flies across compute
    __builtin_amdgcn_sched_barrier(0);
    f32x4 acc = {0, 0, 0, 0};
#pragma unroll
    for (int kkg = 0; kkg < 16; ++kkg) {
      const float* lp = &lds[c & 1][r * 500 + kkg * 32 + g * 8];
      f32x4 v0 = *(const f32x4*)lp;
      f32x4 v1 = *(const f32x4*)(lp + 4);
      float a[8] = {v0.x, v0.y, v0.z, v0.w, v1.x, v1.y, v1.z, v1.w};
      short8 ah, al;
#pragma unroll
      for (int i = 0; i < 8; ++i) {
        ushort_t hi = f2bf(a[i]);
        ah[i] = (short)hi;
        al[i] = (short)f2bf(a[i] - bf2f(hi));
      }
      acc = __builtin_amdgcn_mfma_f32_16x16x32_bf16(ah, Ball[kkg * 2],     acc, 0, 0, 0);
      acc = __builtin_amdgcn_mfma_f32_16x16x32_bf16(al, Ball[kkg * 2],     acc, 0, 0, 0);
      acc = __builtin_amdgcn_mfma_f32_16x16x32_bf16(ah, Ball[kkg * 2 + 1], acc, 0, 0, 0);
    }
    int crow0 = row0 + c * 16;
#pragma unroll
    for (int i = 0; i < 4; ++i) {
      int orow = crow0 + g * 4 + i;          // C/D: row=(lane>>4)*4+reg, col=lane&15
      if (orow < NN) hwb[(size_t)orow * DH + w * 16 + r] = f2bf(acc[i]);
    }
    __syncthreads();                         // drains stage DMA + buffer reuse
  }
}

// Layer-1 aggregate (gather, 16-deep MLP) + bias + ReLU + fused h@W2 -> hw2[v][0..7]
__global__ __launch_bounds__(256) void k_agg1(const ushort_t* __restrict__ hwb,
                                              const int* __restrict__ colsrc,
                                              const int* __restrict__ cnt,
                                              const float* __restrict__ dinv,
                                              const float* __restrict__ b1,
                                              const float* __restrict__ W2,
                                              float* __restrict__ hw2) {
  int lane = threadIdx.x & 63;
  int v = blockIdx.x * 4 + (threadIdx.x >> 6);
  if (v >= NN) return;
  int c = cnt[v]; if (c > MAXDEG) c = MAXDEG;
  float dv = dinv[v];
  const int* cl = colsrc + v * MAXDEG;
  int si = cl[lane];
  bool act = lane < c;
  if (!act) si = 0;
  float nrmv = act ? dinv[si] * dv : 0.0f;
  float acc = 0.0f;
  for (int i0 = 0; i0 < c; i0 += 16) {
    float val[16];
#pragma unroll
    for (int j = 0; j < 16; ++j) {
      int s = __builtin_amdgcn_readlane(si, i0 + j);
      val[j] = bf2f(hwb[(size_t)s * DH + lane]);
    }
#pragma unroll
    for (int j = 0; j < 16; ++j) {
      float nrm = __uint_as_float(__builtin_amdgcn_readlane(__float_as_uint(nrmv), i0 + j));
      acc = fmaf(val[j], nrm, acc);
    }
  }
  float h = acc + b1[lane];
  h = h > 0.0f ? h : 0.0f;
  const float* w2r = W2 + lane * DOUT;
  float p0 = h * w2r[0], p1 = h * w2r[1], p2 = h * w2r[2], p3 = h * w2r[3];
  float p4 = h * w2r[4], p5 = h * w2r[5], p6 = h * w2r[6], p7 = h * w2r[7];
#pragma unroll
  for (int off = 32; off > 0; off >>= 1) {
    p0 += __shfl_xor(p0, off); p1 += __shfl_xor(p1, off);
    p2 += __shfl_xor(p2, off); p3 += __shfl_xor(p3, off);
    p4 += __shfl_xor(p4, off); p5 += __shfl_xor(p5, off);
    p6 += __shfl_xor(p6, off); p7 += __shfl_xor(p7, off);
  }
  if (lane == 0) {
    float4 q0 = {p0, p1, p2, p3}, q1 = {p4, p5, p6, p7};
    *(float4*)(hw2 + (size_t)v * DOUT)     = q0;
    *(float4*)(hw2 + (size_t)v * DOUT + 4) = q1;
  }
}

// Layer-2 aggregate + bias + log_softmax. One WAVE per node: lanes = 8 edges x 8 features.
__global__ __launch_bounds__(256) void k_agg2(const float* __restrict__ hw2,
                                              const int* __restrict__ colsrc,
                                              const int* __restrict__ cnt,
                                              const float* __restrict__ dinv,
                                              const float* __restrict__ b2,
                                              float* __restrict__ out) {
  int lane = threadIdx.x & 63;
  int v = blockIdx.x * 4 + (threadIdx.x >> 6);
  if (v >= NN) return;
  int e = lane >> 3, f = lane & 7;
  int c = cnt[v]; if (c > MAXDEG) c = MAXDEG;
  float dv = dinv[v];
  const int* cl = colsrc + v * MAXDEG;
  float acc = 0.0f;
  for (int i0 = 0; i0 < c; i0 += 8) {
    int i = i0 + e;
    bool a2 = i < c;
    int s = a2 ? cl[i] : 0;
    float nrm = a2 ? dinv[s] * dv : 0.0f;
    float val = hw2[(size_t)s * DOUT + f] * nrm;
    val += __shfl_xor(val, 8);
    val += __shfl_xor(val, 16);
    val += __shfl_xor(val, 32);
    acc += val;
  }
  acc += b2[f];
  float m = acc;
  m = fmaxf(m, __shfl_xor(m, 1));
  m = fmaxf(m, __shfl_xor(m, 2));
  m = fmaxf(m, __shfl_xor(m, 4));
  float ex = expf(acc - m);
  float sum = ex;
  sum += __shfl_xor(sum, 1);
  sum += __shfl_xor(sum, 2);
  sum += __shfl_xor(sum, 4);
  float ls = m + logf(sum);
  if (e == 0) out[(size_t)v * DOUT + f] = acc - ls;
}

extern "C" void kernel_launch(void* const* d_in, const int* in_sizes, int n_in,
                              void* d_out, int out_size, void* d_ws, size_t ws_size,
                              hipStream_t stream) {
  const float* x  = (const float*)d_in[0];
  const int*   ei = (const int*)d_in[1];
  const float* W1 = (const float*)d_in[2];
  const float* b1 = (const float*)d_in[3];
  const float* W2 = (const float*)d_in[4];
  const float* b2 = (const float*)d_in[5];
  float* out = (float*)d_out;

  char* w = (char*)d_ws;
  size_t off = 0;
  auto alloc = [&](size_t bytes) {
    char* p = w + off;
    off += (bytes + 255) & ~(size_t)255;
    return (void*)p;
  };
  int*      cursor = (int*)alloc((size_t)NN * 4);
  float*    dinv   = (float*)alloc((size_t)NN * 4);
  ushort_t* bt     = (ushort_t*)alloc((size_t)DH * KP * 2 * 2);
  int*      colsrc = (int*)alloc((size_t)NN * MAXDEG * 4);
  ushort_t* hwb    = (ushort_t*)alloc((size_t)NN * DH * 2);
  float*    hw2    = (float*)alloc((size_t)NN * DOUT * 4);

  hipMemsetAsync(cursor, 0, (size_t)NN * 4, stream);
  int fill_blocks = (NE + NN + 256 * FILL_EPT - 1) / (256 * FILL_EPT);
  k_fill<<<fill_blocks, 256, 0, stream>>>(ei, cursor, colsrc);
  k_dinv<<<(NN + 255) / 256, 256, 0, stream>>>(cursor, dinv);
  k_w1cvt<<<(DH * KP * 2 + 255) / 256, 256, 0, stream>>>(W1, bt);
  k_gemm1<<<GEMMB, 256, 0, stream>>>(x, bt, hwb);
  k_agg1<<<(NN + 3) / 4, 256, 0, stream>>>(hwb, colsrc, cursor, dinv, b1, W2, hw2);
  k_agg2<<<(NN + 3) / 4, 256, 0, stream>>>(hw2, colsrc, cursor, dinv, b2, out);
}